// Round 10
// baseline (406.499 us; speedup 1.0000x reference)
//
#include <hip/hip_runtime.h>
#include <hip/hip_bf16.h>

typedef __hip_bfloat16 bf16;
typedef __bf16 bf16x8 __attribute__((ext_vector_type(8)));  // MFMA A/B operand
typedef float f32x4 __attribute__((ext_vector_type(4)));

constexpr int Bn = 8, Sn = 2048, Dn = 1024;
constexpr int BM = 128, BN = 128, BK = 64;

// ---------------- cast fp32 -> bf16, vectorized ----------------
__global__ void cast_f32_bf16_k(const float* __restrict__ x, bf16* __restrict__ y, int n) {
  int i = (blockIdx.x * blockDim.x + threadIdx.x) * 4;
  if (i >= n) return;
  float4 f = *reinterpret_cast<const float4*>(x + i);
  bf16 tmp[4] = {__float2bfloat16(f.x), __float2bfloat16(f.y),
                 __float2bfloat16(f.z), __float2bfloat16(f.w)};
  *reinterpret_cast<short4*>(y + i) = *reinterpret_cast<const short4*>(tmp);
}

// ------- transpose+cast: src fp32 [z][R][C] -> dst bf16 [z][C][R] -------
__global__ void transpose_cast_k(const float* __restrict__ src0, bf16* __restrict__ dst0,
                                 int R, int C) {
  __shared__ float tile[32][33];
  const int r0 = blockIdx.x * 32, c0 = blockIdx.y * 32, b = blockIdx.z;
  const float* src = src0 + (size_t)b * R * C;
  bf16* dst = dst0 + (size_t)b * C * R;
  const int tx = threadIdx.x & 31, ty = threadIdx.x >> 5;
  #pragma unroll
  for (int i = 0; i < 4; ++i) {
    int r = ty + i * 8;
    tile[r][tx] = src[(size_t)(r0 + r) * C + c0 + tx];
  }
  __syncthreads();
  #pragma unroll
  for (int i = 0; i < 4; ++i) {
    int c = ty + i * 8;
    dst[(size_t)(c0 + c) * R + r0 + tx] = __float2bfloat16(tile[tx][c]);
  }
}

// ---------------- bc = W2 @ b1 + b2 (fp32) ----------------
__global__ __launch_bounds__(256)
void bias_compose_k(const float* __restrict__ W2, const float* __restrict__ b1,
                    const float* __restrict__ b2, float* __restrict__ bc) {
  const int row = blockIdx.x;
  const int t = threadIdx.x;
  float4 wv = *reinterpret_cast<const float4*>(W2 + (size_t)row * Dn + t * 4);
  float4 bv = *reinterpret_cast<const float4*>(b1 + t * 4);
  float s = wv.x * bv.x + wv.y * bv.y + wv.z * bv.z + wv.w * bv.w;
  #pragma unroll
  for (int off = 32; off >= 1; off >>= 1) s += __shfl_xor(s, off);
  __shared__ float ssum[4];
  if ((t & 63) == 0) ssum[t >> 6] = s;
  __syncthreads();
  if (t == 0) bc[row] = (ssum[0] + ssum[1]) + (ssum[2] + ssum[3]) + b2[row];
}

// ------------ 128x128x64 dbuf GEMM, 2 blocks/CU (R7-validated core): C = A @ BT^T ------------
// LDS byte map (64 KiB): buf*32768 + {A:0, B:16384}
// Race ledger: per iter: issue A/B(T+1 -> buf 1-cur) FIRST; ds_read buf cur;
//   lgkmcnt(0); MFMA; vmcnt(0); [AF32: cvt+ds_write A, lgkmcnt(0)]; s_barrier.
#define SBAR()  asm volatile("s_barrier" ::: "memory")
#define LGKM0() asm volatile("s_waitcnt lgkmcnt(0)" ::: "memory")
#define VM0()   asm volatile("s_waitcnt vmcnt(0)" ::: "memory")

#define MFMA16() do {                                                         \
    __builtin_amdgcn_s_setprio(1);                                            \
    _Pragma("unroll")                                                         \
    for (int kk = 0; kk < 2; ++kk)                                            \
      _Pragma("unroll")                                                       \
      for (int mi4 = 0; mi4 < 4; ++mi4)                                       \
        _Pragma("unroll")                                                     \
        for (int n2 = 0; n2 < 2; ++n2)                                        \
          acc[mi4][n2] = __builtin_amdgcn_mfma_f32_16x16x32_bf16(             \
              aF[mi4][kk], bF[n2][kk], acc[mi4][n2], 0, 0, 0);                \
    __builtin_amdgcn_s_setprio(0);                                            \
  } while (0)

#define ITER(cur, T) do {                                                     \
    const bool pf = (T) + 1 < NT;                                             \
    float4 a0, a1, a2, a3;                                                    \
    if (pf) {                                                                 \
      if constexpr (AF32) {                                                   \
        const float* gf = Af + (size_t)((T) + 1) * BK;                        \
        a0 = *reinterpret_cast<const float4*>(gf + gOffF[0]);                 \
        a1 = *reinterpret_cast<const float4*>(gf + gOffF[0] + 4);             \
        a2 = *reinterpret_cast<const float4*>(gf + gOffF[1]);                 \
        a3 = *reinterpret_cast<const float4*>(gf + gOffF[1] + 4);             \
      } else {                                                                \
        stage2((1 - (cur)) * 32768, Abase, (T) + 1);                          \
      }                                                                       \
      stage2((1 - (cur)) * 32768 + 16384, Bbase, (T) + 1);                    \
    }                                                                         \
    _Pragma("unroll")                                                         \
    for (int mi4 = 0; mi4 < 4; ++mi4) {                                       \
      aF[mi4][0] = *reinterpret_cast<const bf16x8*>(pA0 + (cur)*32768 + mi4*2048); \
      aF[mi4][1] = *reinterpret_cast<const bf16x8*>(pA1 + (cur)*32768 + mi4*2048); \
    }                                                                         \
    _Pragma("unroll")                                                         \
    for (int j = 0; j < 2; ++j) {                                             \
      bF[j][0] = *reinterpret_cast<const bf16x8*>(pB0 + (cur)*32768 + j*2048); \
      bF[j][1] = *reinterpret_cast<const bf16x8*>(pB1 + (cur)*32768 + j*2048); \
    }                                                                         \
    LGKM0();                                                                  \
    MFMA16();                                                                 \
    if (pf) {                                                                 \
      VM0();                                                                  \
      if constexpr (AF32) {                                                   \
        wrA((1 - (cur)) * 32768, a0, a1, a2, a3);                             \
        LGKM0();                                                              \
      }                                                                       \
    }                                                                         \
    SBAR();                                                                   \
  } while (0)

// EPI 0: C_bf16 = acc + bias_f32[col]
// EPI 1: C_bf16 = exp(acc*scale + mask_bf16[row*N+col])
// EPI 2: C_f32  = acc / Z[z*Sn + row]
// EPI 3: C_bf16 = acc
template<int EPI, bool AF32>
__global__ __launch_bounds__(512, 4)
void gemm128_k(const bf16* __restrict__ A,
               const float* __restrict__ Aq, const float* __restrict__ Ak, int rowSplit,
               const bf16* __restrict__ BT,
               void* __restrict__ Cv, const void* __restrict__ auxv,
               int N, int K, long long sAz, long long sBz, long long sCz,
               float scale, int gx, int gy)
{
  __shared__ __align__(128) bf16 sh[2 * 16384];   // 64 KiB -> 2 blocks/CU

  // T1: XCD-aware bijective swizzle (nwg % 8 == 0 for all launches here)
  const int nwg = (int)gridDim.x;
  const int flat = (int)blockIdx.x;
  const int swz = (flat & 7) * (nwg >> 3) + (flat >> 3);
  const int tn = swz % gx;
  const int rem = swz / gx;
  const int tm = rem % gy;
  const int z  = rem / gy;

  const int t = threadIdx.x, w = t >> 6, lane = t & 63;
  const int wm = w >> 2, wn = w & 3;              // 2 x 4 wave grid; wave tile 64x32
  const int fr = lane & 15, kg = lane >> 4;
  const int m0 = tm * BM, n0 = tn * BN;
  const bf16* Abase = A + (size_t)z * sAz + (size_t)m0 * K;
  const bf16* Bbase = BT + (size_t)z * sBz + (size_t)n0 * K;
  const float* Af = nullptr;
  if constexpr (AF32)
    Af = (m0 < rowSplit) ? Aq + (size_t)m0 * K : Ak + (size_t)(m0 - rowSplit) * K;

  f32x4 acc[4][2];
  const f32x4 fz = {0.f, 0.f, 0.f, 0.f};
  #pragma unroll
  for (int i = 0; i < 4; ++i) { acc[i][0] = fz; acc[i][1] = fz; }
  bf16x8 aF[4][2], bF[2][2];

  // hoisted per-thread LDS read bases; swizzle byte ^= (row&7)<<4 folded in
  const char* shB = (const char*)sh;
  const int swzlo = (fr & 3) << 4;                // XOR bits 4-5
  const int swzhi = (fr & 4) << 4;                // XOR bit 6
  const int aoff0 = (wm * 64 + fr) * 128 + ((kg * 16) ^ swzlo) + swzhi;
  const int boff0 = 16384 + (wn * 32 + fr) * 128 + ((kg * 16) ^ swzlo) + swzhi;
  const char* pA0 = shB + aoff0;
  const char* pA1 = shB + (aoff0 ^ 64);           // kk=1 flips bit 6
  const char* pB0 = shB + boff0;
  const char* pB1 = shB + (boff0 ^ 64);

  // hoisted per-thread staging offsets (source pre-swizzled, dest linear)
  int gOff[2], gOffF[2];
  #pragma unroll
  for (int i = 0; i < 2; ++i) {
    const int slot = i * 512 + w * 64 + lane;     // 0..1023 -> 128 rows x 64 cols
    const int row = slot >> 3;
    const int cb = (slot & 7) ^ (row & 7);        // inverse of read-side XOR
    gOff[i]  = row * K + cb * 8;
    gOffF[i] = row * K + cb * 8;                  // same (elements)
  }
  auto stage2 = [&](int dstByte, const bf16* gbase, int kt) {
    const bf16* g0 = gbase + (size_t)kt * BK;
    char* db = (char*)sh + dstByte;
    #pragma unroll
    for (int i = 0; i < 2; ++i) {
      __builtin_amdgcn_global_load_lds(
          (__attribute__((address_space(1))) void*)(g0 + gOff[i]),
          (__attribute__((address_space(3))) void*)(db + (i * 512 + w * 64) * 16),
          16, 0, 0);
    }
  };
  // convert 16 staged fp32 -> bf16 and ds_write to the two linear dest slots
  auto wrA = [&](int dstByte, float4 x0, float4 x1, float4 x2, float4 x3) {
    char* db = (char*)sh + dstByte;
    bf16 tmp[16] = {
      __float2bfloat16(x0.x), __float2bfloat16(x0.y), __float2bfloat16(x0.z), __float2bfloat16(x0.w),
      __float2bfloat16(x1.x), __float2bfloat16(x1.y), __float2bfloat16(x1.z), __float2bfloat16(x1.w),
      __float2bfloat16(x2.x), __float2bfloat16(x2.y), __float2bfloat16(x2.z), __float2bfloat16(x2.w),
      __float2bfloat16(x3.x), __float2bfloat16(x3.y), __float2bfloat16(x3.z), __float2bfloat16(x3.w)};
    *reinterpret_cast<int4*>(db + (0 * 512 + t) * 16) = *reinterpret_cast<const int4*>(tmp);
    *reinterpret_cast<int4*>(db + (1 * 512 + t) * 16) = *reinterpret_cast<const int4*>(tmp + 8);
  };

  const int NT = K / BK;                          // even
  // prologue: tile0 -> buf0
  if constexpr (AF32) {
    float4 a0 = *reinterpret_cast<const float4*>(Af + gOffF[0]);
    float4 a1 = *reinterpret_cast<const float4*>(Af + gOffF[0] + 4);
    float4 a2 = *reinterpret_cast<const float4*>(Af + gOffF[1]);
    float4 a3 = *reinterpret_cast<const float4*>(Af + gOffF[1] + 4);
    stage2(16384, Bbase, 0);
    wrA(0, a0, a1, a2, a3);
    VM0(); LGKM0(); SBAR();
  } else {
    stage2(0,     Abase, 0);
    stage2(16384, Bbase, 0);
    VM0(); SBAR();
  }

  for (int T = 0; T < NT; T += 2) {
    ITER(0, T);
    ITER(1, T + 1);
  }

  // epilogue: frag (mi,nj): C[m0+wm*64+mi*16+kg*4+r][n0+wn*32+nj*16+fr]
  const int or0 = kg * 4;
  if constexpr (EPI == 0) {
    bf16* C = (bf16*)Cv + (size_t)z * sCz;
    const float* aux = (const float*)auxv;
    #pragma unroll
    for (int mi = 0; mi < 4; ++mi)
      #pragma unroll
      for (int r = 0; r < 4; ++r) {
        const int row = m0 + wm * 64 + mi * 16 + or0 + r;
        #pragma unroll
        for (int nj = 0; nj < 2; ++nj) {
          const int col = n0 + wn * 32 + nj * 16 + fr;
          C[(size_t)row * N + col] = __float2bfloat16(acc[mi][nj][r] + aux[col]);
        }
      }
  } else if constexpr (EPI == 1) {
    bf16* C = (bf16*)Cv + (size_t)z * sCz;
    const bf16* M = (const bf16*)auxv;
    #pragma unroll
    for (int mi = 0; mi < 4; ++mi)
      #pragma unroll
      for (int r = 0; r < 4; ++r) {
        const int row = m0 + wm * 64 + mi * 16 + or0 + r;
        #pragma unroll
        for (int nj = 0; nj < 2; ++nj) {
          const int col = n0 + wn * 32 + nj * 16 + fr;
          float mv = __bfloat162float(M[(size_t)row * N + col]);
          float v = __expf(acc[mi][nj][r] * scale + mv);
          C[(size_t)row * N + col] = __float2bfloat16(v);
        }
      }
  } else if constexpr (EPI == 2) {
    float* C = (float*)Cv + (size_t)z * sCz;
    const float* Zb = (const float*)auxv + (size_t)z * Sn;
    #pragma unroll
    for (int mi = 0; mi < 4; ++mi)
      #pragma unroll
      for (int r = 0; r < 4; ++r) {
        const int row = m0 + wm * 64 + mi * 16 + or0 + r;
        const float invZ = 1.0f / Zb[row];
        #pragma unroll
        for (int nj = 0; nj < 2; ++nj) {
          const int col = n0 + wn * 32 + nj * 16 + fr;
          C[(size_t)row * N + col] = acc[mi][nj][r] * invZ;
        }
      }
  } else {
    bf16* C = (bf16*)Cv + (size_t)z * sCz;
    #pragma unroll
    for (int mi = 0; mi < 4; ++mi)
      #pragma unroll
      for (int r = 0; r < 4; ++r) {
        const int row = m0 + wm * 64 + mi * 16 + or0 + r;
        #pragma unroll
        for (int nj = 0; nj < 2; ++nj) {
          const int col = n0 + wn * 32 + nj * 16 + fr;
          C[(size_t)row * N + col] = __float2bfloat16(acc[mi][nj][r]);
        }
      }
  }
}

// ---------------- row sum of exp-scores: Z[row] = sum of 2048 bf16 ----------------
__global__ __launch_bounds__(256)
void rowsum_k(const bf16* __restrict__ sc, float* __restrict__ Z) {
  const size_t row = blockIdx.x;
  const bf16* p = sc + row * (size_t)Sn;
  const int t = threadIdx.x;
  unsigned short raw[8];
  *reinterpret_cast<int4*>(raw) = *reinterpret_cast<const int4*>(p + t * 8);
  float s = 0.f;
  #pragma unroll
  for (int j = 0; j < 8; ++j) s += __uint_as_float(((unsigned)raw[j]) << 16);
  #pragma unroll
  for (int off = 32; off >= 1; off >>= 1) s += __shfl_xor(s, off);
  __shared__ float ssum[4];
  if ((t & 63) == 0) ssum[t >> 6] = s;
  __syncthreads();
  if (t == 0) Z[row] = (ssum[0] + ssum[1]) + (ssum[2] + ssum[3]);
}

extern "C" void kernel_launch(void* const* d_in, const int* in_sizes, int n_in,
                              void* d_out, int out_size, void* d_ws, size_t ws_size,
                              hipStream_t stream) {
  const float* q    = (const float*)d_in[0];
  const float* k    = (const float*)d_in[1];
  const float* v1   = (const float*)d_in[2];
  const float* mask = (const float*)d_in[3];
  const float* W1   = (const float*)d_in[4];
  const float* b1   = (const float*)d_in[5];
  const float* W2   = (const float*)d_in[6];
  const float* b2   = (const float*)d_in[7];
  float* out = (float*)d_out;

  const size_t nQKD = (size_t)Bn * Sn * Dn;   // 16,777,216
  char* ws = (char*)d_ws;
  bf16* vtb   = (bf16*)ws;                    // V^T [B][D][S]
  bf16* hb    = vtb + nQKD;                   // [qp;kp], 2*nQKD
  bf16* w1t   = hb + 2 * nQKD;                // W1^T bf16
  bf16* w2b   = w1t + (size_t)Dn * Dn;        // W2 bf16
  bf16* wcb   = w2b + (size_t)Dn * Dn;        // Wc = W2@W1 bf16
  bf16* maskb = wcb + (size_t)Dn * Dn;        // mask bf16 [S][S]
  bf16* scb   = maskb + (size_t)Sn * Sn;      // [B][S][S] exp-scores
  float* Zb   = (float*)(scb + (size_t)Bn * Sn * Sn);  // [B*S] row sums
  float* bcb  = Zb + (size_t)Bn * Sn;         // composite bias [1024] fp32

  dim3 blk(256);
  // prep: W2 bf16, W1^T bf16, V^T bf16, mask bf16, bc
  cast_f32_bf16_k<<<dim3(Dn * Dn / 4 / 256), blk, 0, stream>>>(W2, w2b, Dn * Dn);
  cast_f32_bf16_k<<<dim3(Sn * Sn / 4 / 256), blk, 0, stream>>>(mask, maskb, Sn * Sn);
  transpose_cast_k<<<dim3(Dn / 32, Dn / 32, 1), blk, 0, stream>>>(W1, w1t, Dn, Dn);
  transpose_cast_k<<<dim3(Sn / 32, Dn / 32, Bn), blk, 0, stream>>>(v1, vtb, Sn, Dn);
  bias_compose_k<<<dim3(Dn), blk, 0, stream>>>(W2, b1, b2, bcb);

  const int M2 = 2 * Bn * Sn;  // 32768 rows ([q;k] together)
  dim3 gblk(512);
  // Wc = W2 @ (W1^T)^T : grid 8 x 8 = 64
  gemm128_k<3, false><<<dim3(8 * 8), gblk, 0, stream>>>(
      w2b, nullptr, nullptr, 0, w1t, wcb, nullptr, Dn, Dn, 0, 0, 0, 1.f, 8, 8);
  // [qp;kp] = [q;k](fp32, cast fused) @ Wc^T + bc : grid 8 x 256 = 2048
  gemm128_k<0, true><<<dim3(8 * (M2 / 128)), gblk, 0, stream>>>(
      nullptr, q, k, Bn * Sn, wcb, hb, bcb, Dn, Dn, 0, 0, 0, 1.f, 8, M2 / 128);
  // P' = exp(qp @ kp^T / 32 + mask_bf16) : grid 16 x 16 x 8 = 2048
  gemm128_k<1, false><<<dim3(16 * 16 * Bn), gblk, 0, stream>>>(
      hb, nullptr, nullptr, 0, hb + nQKD, scb, maskb, Sn, Dn,
      (long long)Sn * Dn, (long long)Sn * Dn, (long long)Sn * Sn, 0.03125f, 16, 16);
  // Z[row] = sum_k P'[row,k]
  rowsum_k<<<dim3(Bn * Sn), blk, 0, stream>>>(scb, Zb);
  // out = (P' @ V) / Z via VT : grid 8 x 16 x 8 = 1024
  gemm128_k<2, false><<<dim3(8 * 16 * Bn), gblk, 0, stream>>>(
      scb, nullptr, nullptr, 0, vtb, out, Zb, Dn, Sn,
      (long long)Sn * Sn, (long long)Dn * Sn, (long long)Sn * Dn, 1.f, 8, 16);
}

// Round 11
// 318.627 us; speedup vs baseline: 1.2758x; 1.2758x over previous
//
#include <hip/hip_runtime.h>
#include <hip/hip_bf16.h>

typedef __hip_bfloat16 bf16;
typedef __bf16 bf16x8 __attribute__((ext_vector_type(8)));  // MFMA A/B operand
typedef float f32x4 __attribute__((ext_vector_type(4)));

constexpr int Bn = 8, Sn = 2048, Dn = 1024;
constexpr int BM = 128, BN = 128, BK = 64;

// ---------------- cast fp32 -> bf16, vectorized ----------------
__global__ void cast_f32_bf16_k(const float* __restrict__ x, bf16* __restrict__ y, int n) {
  int i = (blockIdx.x * blockDim.x + threadIdx.x) * 4;
  if (i >= n) return;
  float4 f = *reinterpret_cast<const float4*>(x + i);
  bf16 tmp[4] = {__float2bfloat16(f.x), __float2bfloat16(f.y),
                 __float2bfloat16(f.z), __float2bfloat16(f.w)};
  *reinterpret_cast<short4*>(y + i) = *reinterpret_cast<const short4*>(tmp);
}

// ------- transpose+cast: src fp32 [z][R][C] -> dst bf16 [z][C][R] -------
__global__ void transpose_cast_k(const float* __restrict__ src0, bf16* __restrict__ dst0,
                                 int R, int C) {
  __shared__ float tile[32][33];
  const int r0 = blockIdx.x * 32, c0 = blockIdx.y * 32, b = blockIdx.z;
  const float* src = src0 + (size_t)b * R * C;
  bf16* dst = dst0 + (size_t)b * C * R;
  const int tx = threadIdx.x & 31, ty = threadIdx.x >> 5;
  #pragma unroll
  for (int i = 0; i < 4; ++i) {
    int r = ty + i * 8;
    tile[r][tx] = src[(size_t)(r0 + r) * C + c0 + tx];
  }
  __syncthreads();
  #pragma unroll
  for (int i = 0; i < 4; ++i) {
    int c = ty + i * 8;
    dst[(size_t)(c0 + c) * R + r0 + tx] = __float2bfloat16(tile[tx][c]);
  }
}

// ---------------- bc = W2 @ b1 + b2 (fp32) ----------------
__global__ __launch_bounds__(256)
void bias_compose_k(const float* __restrict__ W2, const float* __restrict__ b1,
                    const float* __restrict__ b2, float* __restrict__ bc) {
  const int row = blockIdx.x;
  const int t = threadIdx.x;
  float4 wv = *reinterpret_cast<const float4*>(W2 + (size_t)row * Dn + t * 4);
  float4 bv = *reinterpret_cast<const float4*>(b1 + t * 4);
  float s = wv.x * bv.x + wv.y * bv.y + wv.z * bv.z + wv.w * bv.w;
  #pragma unroll
  for (int off = 32; off >= 1; off >>= 1) s += __shfl_xor(s, off);
  __shared__ float ssum[4];
  if ((t & 63) == 0) ssum[t >> 6] = s;
  __syncthreads();
  if (t == 0) bc[row] = (ssum[0] + ssum[1]) + (ssum[2] + ssum[3]) + b2[row];
}

// ---------------- u[i] = (Wc^T bc)[i] via WcT rows (bf16) ----------------
__global__ __launch_bounds__(256)
void udot_k(const bf16* __restrict__ wct, const float* __restrict__ bc,
            float* __restrict__ u) {
  const int i = blockIdx.x, t = threadIdx.x;
  short4 wv = *reinterpret_cast<const short4*>(wct + (size_t)i * Dn + t * 4);
  float4 bv = *reinterpret_cast<const float4*>(bc + t * 4);
  float s = __uint_as_float(((unsigned)(unsigned short)wv.x) << 16) * bv.x
          + __uint_as_float(((unsigned)(unsigned short)wv.y) << 16) * bv.y
          + __uint_as_float(((unsigned)(unsigned short)wv.z) << 16) * bv.z
          + __uint_as_float(((unsigned)(unsigned short)wv.w) << 16) * bv.w;
  #pragma unroll
  for (int off = 32; off >= 1; off >>= 1) s += __shfl_xor(s, off);
  __shared__ float ssum[4];
  if ((t & 63) == 0) ssum[t >> 6] = s;
  __syncthreads();
  if (t == 0) u[i] = (ssum[0] + ssum[1]) + (ssum[2] + ssum[3]);
}

// ---------------- c0 = |bc|^2 ----------------
__global__ __launch_bounds__(256)
void c0_k(const float* __restrict__ bc, float* __restrict__ c0) {
  const int t = threadIdx.x;
  float4 bv = *reinterpret_cast<const float4*>(bc + t * 4);
  float s = bv.x * bv.x + bv.y * bv.y + bv.z * bv.z + bv.w * bv.w;
  #pragma unroll
  for (int off = 32; off >= 1; off >>= 1) s += __shfl_xor(s, off);
  __shared__ float ssum[4];
  if ((t & 63) == 0) ssum[t >> 6] = s;
  __syncthreads();
  if (t == 0) c0[0] = (ssum[0] + ssum[1]) + (ssum[2] + ssum[3]);
}

// ---- cast q|k rows -> bf16 AND per-row dot with u: qu[r]=q_r.u + c0, ku[r]=k_r.u ----
__global__ __launch_bounds__(256)
void castdot_k(const float* __restrict__ q, const float* __restrict__ k,
               const float* __restrict__ u, const float* __restrict__ c0,
               bf16* __restrict__ dst, float* __restrict__ qu, float* __restrict__ ku) {
  const int row = blockIdx.x;                 // 0 .. 2*Bn*Sn-1
  const bool isQ = row < Bn * Sn;
  const float* src = isQ ? q + (size_t)row * Dn : k + (size_t)(row - Bn * Sn) * Dn;
  const int t = threadIdx.x;
  float4 f = *reinterpret_cast<const float4*>(src + t * 4);
  bf16 tmp[4] = {__float2bfloat16(f.x), __float2bfloat16(f.y),
                 __float2bfloat16(f.z), __float2bfloat16(f.w)};
  *reinterpret_cast<short4*>(dst + (size_t)row * Dn + t * 4) =
      *reinterpret_cast<const short4*>(tmp);
  float4 uv = *reinterpret_cast<const float4*>(u + t * 4);
  float s = f.x * uv.x + f.y * uv.y + f.z * uv.z + f.w * uv.w;
  #pragma unroll
  for (int off = 32; off >= 1; off >>= 1) s += __shfl_xor(s, off);
  __shared__ float ssum[4];
  if ((t & 63) == 0) ssum[t >> 6] = s;
  __syncthreads();
  if (t == 0) {
    float tot = (ssum[0] + ssum[1]) + (ssum[2] + ssum[3]);
    if (isQ) qu[row] = tot + c0[0];
    else     ku[row - Bn * Sn] = tot;
  }
}

// ------------ 128x128x64 dbuf GEMM, 2 blocks/CU (R7/R9-validated core): C = A @ BT^T ------------
// LDS byte map (64 KiB): buf*32768 + {A:0, B:16384}
// Race ledger: per iter: stage(T+1 -> buf 1-cur) FIRST; ds_read buf cur;
//   lgkmcnt(0); MFMA; vmcnt(0) [drain own stage]; s_barrier.
#define SBAR()  asm volatile("s_barrier" ::: "memory")
#define LGKM0() asm volatile("s_waitcnt lgkmcnt(0)" ::: "memory")
#define VM0()   asm volatile("s_waitcnt vmcnt(0)" ::: "memory")

#define MFMA16() do {                                                         \
    __builtin_amdgcn_s_setprio(1);                                            \
    _Pragma("unroll")                                                         \
    for (int kk = 0; kk < 2; ++kk)                                            \
      _Pragma("unroll")                                                       \
      for (int mi4 = 0; mi4 < 4; ++mi4)                                       \
        _Pragma("unroll")                                                     \
        for (int n2 = 0; n2 < 2; ++n2)                                        \
          acc[mi4][n2] = __builtin_amdgcn_mfma_f32_16x16x32_bf16(             \
              aF[mi4][kk], bF[n2][kk], acc[mi4][n2], 0, 0, 0);                \
    __builtin_amdgcn_s_setprio(0);                                            \
  } while (0)

#define ITER(cur, T) do {                                                     \
    const bool pf = (T) + 1 < NT;                                             \
    if (pf) {                                                                 \
      stage2((1 - (cur)) * 32768,         Abase, (T) + 1);                    \
      stage2((1 - (cur)) * 32768 + 16384, Bbase, (T) + 1);                    \
    }                                                                         \
    _Pragma("unroll")                                                         \
    for (int mi4 = 0; mi4 < 4; ++mi4) {                                       \
      aF[mi4][0] = *reinterpret_cast<const bf16x8*>(pA0 + (cur)*32768 + mi4*2048); \
      aF[mi4][1] = *reinterpret_cast<const bf16x8*>(pA1 + (cur)*32768 + mi4*2048); \
    }                                                                         \
    _Pragma("unroll")                                                         \
    for (int j = 0; j < 2; ++j) {                                             \
      bF[j][0] = *reinterpret_cast<const bf16x8*>(pB0 + (cur)*32768 + j*2048); \
      bF[j][1] = *reinterpret_cast<const bf16x8*>(pB1 + (cur)*32768 + j*2048); \
    }                                                                         \
    LGKM0();                                                                  \
    MFMA16();                                                                 \
    if (pf) VM0();                                                            \
    SBAR();                                                                   \
  } while (0)

// EPI 1: C_bf16 = exp((acc + qu[z,row] + ku[z,col]) * scale + mask_f32[row*N+col])
// EPI 2: C_f32  = acc / Z[z*Sn + row]
// EPI 3: C_bf16 = acc
// EPI 4: C_bf16 = acc, and CT_bf16[col*N+row] = acc (square N)
template<int EPI>
__global__ __launch_bounds__(512, 4)
void gemm128_k(const bf16* __restrict__ A, const bf16* __restrict__ BT,
               void* __restrict__ Cv, const void* __restrict__ auxv,
               const float* __restrict__ qu, const float* __restrict__ ku,
               int N, int K, long long sAz, long long sBz, long long sCz,
               float scale, int gx, int gy)
{
  __shared__ __align__(128) bf16 sh[2 * 16384];   // 64 KiB -> 2 blocks/CU

  // T1: XCD-aware bijective swizzle (nwg % 8 == 0 for all launches here)
  const int nwg = (int)gridDim.x;
  const int flat = (int)blockIdx.x;
  const int swz = (flat & 7) * (nwg >> 3) + (flat >> 3);
  const int tn = swz % gx;
  const int rem = swz / gx;
  const int tm = rem % gy;
  const int z  = rem / gy;

  const int t = threadIdx.x, w = t >> 6, lane = t & 63;
  const int wm = w >> 2, wn = w & 3;              // 2 x 4 wave grid; wave tile 64x32
  const int fr = lane & 15, kg = lane >> 4;
  const int m0 = tm * BM, n0 = tn * BN;
  const bf16* Abase = A + (size_t)z * sAz + (size_t)m0 * K;
  const bf16* Bbase = BT + (size_t)z * sBz + (size_t)n0 * K;

  f32x4 acc[4][2];
  const f32x4 fz = {0.f, 0.f, 0.f, 0.f};
  #pragma unroll
  for (int i = 0; i < 4; ++i) { acc[i][0] = fz; acc[i][1] = fz; }
  bf16x8 aF[4][2], bF[2][2];

  // hoisted per-thread LDS read bases; swizzle byte ^= (row&7)<<4 folded in
  const char* shB = (const char*)sh;
  const int swzlo = (fr & 3) << 4;                // XOR bits 4-5
  const int swzhi = (fr & 4) << 4;                // XOR bit 6
  const int aoff0 = (wm * 64 + fr) * 128 + ((kg * 16) ^ swzlo) + swzhi;
  const int boff0 = 16384 + (wn * 32 + fr) * 128 + ((kg * 16) ^ swzlo) + swzhi;
  const char* pA0 = shB + aoff0;
  const char* pA1 = shB + (aoff0 ^ 64);           // kk=1 flips bit 6
  const char* pB0 = shB + boff0;
  const char* pB1 = shB + (boff0 ^ 64);

  // hoisted per-thread staging offsets (source pre-swizzled, dest linear)
  int gOff[2];
  #pragma unroll
  for (int i = 0; i < 2; ++i) {
    const int slot = i * 512 + w * 64 + lane;     // 0..1023 -> 128 rows x 64 cols
    const int row = slot >> 3;
    const int cb = (slot & 7) ^ (row & 7);        // inverse of read-side XOR
    gOff[i] = row * K + cb * 8;
  }
  auto stage2 = [&](int dstByte, const bf16* gbase, int kt) {
    const bf16* g0 = gbase + (size_t)kt * BK;
    char* db = (char*)sh + dstByte;
    #pragma unroll
    for (int i = 0; i < 2; ++i) {
      __builtin_amdgcn_global_load_lds(
          (__attribute__((address_space(1))) void*)(g0 + gOff[i]),
          (__attribute__((address_space(3))) void*)(db + (i * 512 + w * 64) * 16),
          16, 0, 0);
    }
  };

  const int NT = K / BK;                          // even
  stage2(0,     Abase, 0);
  stage2(16384, Bbase, 0);
  VM0();
  SBAR();

  for (int T = 0; T < NT; T += 2) {
    ITER(0, T);
    ITER(1, T + 1);
  }

  // epilogue: frag (mi,nj): C[m0+wm*64+mi*16+kg*4+r][n0+wn*32+nj*16+fr]
  const int or0 = kg * 4;
  if constexpr (EPI == 1) {
    bf16* C = (bf16*)Cv + (size_t)z * sCz;
    const float* M = (const float*)auxv;
    const float* quz = qu + (size_t)z * Sn;
    const float* kuz = ku + (size_t)z * Sn;
    #pragma unroll
    for (int mi = 0; mi < 4; ++mi)
      #pragma unroll
      for (int r = 0; r < 4; ++r) {
        const int row = m0 + wm * 64 + mi * 16 + or0 + r;
        const float quv = quz[row];
        #pragma unroll
        for (int nj = 0; nj < 2; ++nj) {
          const int col = n0 + wn * 32 + nj * 16 + fr;
          float v = __expf((acc[mi][nj][r] + quv + kuz[col]) * scale
                           + M[(size_t)row * N + col]);
          C[(size_t)row * N + col] = __float2bfloat16(v);
        }
      }
  } else if constexpr (EPI == 2) {
    float* C = (float*)Cv + (size_t)z * sCz;
    const float* Zb = (const float*)auxv + (size_t)z * Sn;
    #pragma unroll
    for (int mi = 0; mi < 4; ++mi)
      #pragma unroll
      for (int r = 0; r < 4; ++r) {
        const int row = m0 + wm * 64 + mi * 16 + or0 + r;
        const float invZ = 1.0f / Zb[row];
        #pragma unroll
        for (int nj = 0; nj < 2; ++nj) {
          const int col = n0 + wn * 32 + nj * 16 + fr;
          C[(size_t)row * N + col] = acc[mi][nj][r] * invZ;
        }
      }
  } else {
    bf16* C = (bf16*)Cv + (size_t)z * sCz;
    bf16* CT = (EPI == 4) ? (bf16*)const_cast<void*>(auxv) : nullptr;
    #pragma unroll
    for (int mi = 0; mi < 4; ++mi)
      #pragma unroll
      for (int r = 0; r < 4; ++r) {
        const int row = m0 + wm * 64 + mi * 16 + or0 + r;
        #pragma unroll
        for (int nj = 0; nj < 2; ++nj) {
          const int col = n0 + wn * 32 + nj * 16 + fr;
          const bf16 v = __float2bfloat16(acc[mi][nj][r]);
          C[(size_t)row * N + col] = v;
          if constexpr (EPI == 4) CT[(size_t)col * N + row] = v;
        }
      }
  }
}

// ---------------- row sum of exp-scores: Z[row] = sum of 2048 bf16 ----------------
__global__ __launch_bounds__(256)
void rowsum_k(const bf16* __restrict__ sc, float* __restrict__ Z) {
  const size_t row = blockIdx.x;
  const bf16* p = sc + row * (size_t)Sn;
  const int t = threadIdx.x;
  unsigned short raw[8];
  *reinterpret_cast<int4*>(raw) = *reinterpret_cast<const int4*>(p + t * 8);
  float s = 0.f;
  #pragma unroll
  for (int j = 0; j < 8; ++j) s += __uint_as_float(((unsigned)raw[j]) << 16);
  #pragma unroll
  for (int off = 32; off >= 1; off >>= 1) s += __shfl_xor(s, off);
  __shared__ float ssum[4];
  if ((t & 63) == 0) ssum[t >> 6] = s;
  __syncthreads();
  if (t == 0) Z[row] = (ssum[0] + ssum[1]) + (ssum[2] + ssum[3]);
}

extern "C" void kernel_launch(void* const* d_in, const int* in_sizes, int n_in,
                              void* d_out, int out_size, void* d_ws, size_t ws_size,
                              hipStream_t stream) {
  const float* q    = (const float*)d_in[0];
  const float* k    = (const float*)d_in[1];
  const float* v1   = (const float*)d_in[2];
  const float* mask = (const float*)d_in[3];
  const float* W1   = (const float*)d_in[4];
  const float* b1   = (const float*)d_in[5];
  const float* W2   = (const float*)d_in[6];
  const float* b2   = (const float*)d_in[7];
  float* out = (float*)d_out;

  const size_t nQKD = (size_t)Bn * Sn * Dn;   // 16,777,216
  const size_t nDD = (size_t)Dn * Dn;
  char* ws = (char*)d_ws;
  bf16* vtb  = (bf16*)ws;                     // V^T [B][D][S]
  bf16* qkb  = vtb + nQKD;                    // [q;k] bf16, 2*nQKD
  bf16* kgb  = qkb + 2 * nQKD;                // kg = k @ G, [B][S][D]
  bf16* w1t  = kgb + nQKD;                    // W1^T bf16
  bf16* w2b  = w1t + nDD;                     // W2 bf16
  bf16* wcb  = w2b + nDD;                     // Wc = W2@W1
  bf16* wct  = wcb + nDD;                     // Wc^T
  bf16* gb   = wct + nDD;                     // G = Wc^T @ Wc
  bf16* scb  = gb + nDD;                      // [B][S][S] exp-scores
  float* Zb  = (float*)(scb + (size_t)Bn * Sn * Sn);  // [B*S]
  float* qub = Zb + (size_t)Bn * Sn;          // [B*S] q.u + c0
  float* kub = qub + (size_t)Bn * Sn;         // [B*S] k.u
  float* bcb = kub + (size_t)Bn * Sn;         // [1024]
  float* ub  = bcb + Dn;                      // [1024]
  float* c0v = ub + Dn;                       // [1]

  dim3 blk(256);
  // prep
  cast_f32_bf16_k<<<dim3(Dn * Dn / 4 / 256), blk, 0, stream>>>(W2, w2b, Dn * Dn);
  transpose_cast_k<<<dim3(Dn / 32, Dn / 32, 1), blk, 0, stream>>>(W1, w1t, Dn, Dn);
  transpose_cast_k<<<dim3(Sn / 32, Dn / 32, Bn), blk, 0, stream>>>(v1, vtb, Sn, Dn);
  bias_compose_k<<<dim3(Dn), blk, 0, stream>>>(W2, b1, b2, bcb);

  dim3 gblk(512);
  // Wc = W2 @ (W1^T)^T, also write Wc^T : grid 8 x 8 = 64
  gemm128_k<4><<<dim3(8 * 8), gblk, 0, stream>>>(
      w2b, w1t, wcb, wct, nullptr, nullptr, Dn, Dn, 0, 0, 0, 1.f, 8, 8);
  // G = Wc^T @ (Wc^T)^T = Wc^T Wc : grid 64
  gemm128_k<3><<<dim3(8 * 8), gblk, 0, stream>>>(
      wct, wct, gb, nullptr, nullptr, nullptr, Dn, Dn, 0, 0, 0, 1.f, 8, 8);
  // u = Wc^T bc ; c0 = |bc|^2
  udot_k<<<dim3(Dn), blk, 0, stream>>>(wct, bcb, ub);
  c0_k<<<dim3(1), blk, 0, stream>>>(bcb, c0v);
  // cast q|k -> bf16 + row dots with u
  castdot_k<<<dim3(2 * Bn * Sn), blk, 0, stream>>>(q, k, ub, c0v, qkb, qub, kub);
  // kg = k @ G (G symmetric) : M = 16384 flat, grid 8 x 128 = 1024
  gemm128_k<3><<<dim3(8 * 128), gblk, 0, stream>>>(
      qkb + nQKD, gb, kgb, nullptr, nullptr, nullptr, Dn, Dn, 0, 0, 0, 1.f, 8, 128);
  // P' = exp((q @ kg^T + qu + ku) / 32 + mask) : grid 16 x 16 x 8 = 2048
  gemm128_k<1><<<dim3(16 * 16 * Bn), gblk, 0, stream>>>(
      qkb, kgb, scb, mask, qub, kub, Sn, Dn,
      (long long)Sn * Dn, (long long)Sn * Dn, (long long)Sn * Sn, 0.03125f, 16, 16);
  // Z[row] = sum_k P'[row,k]
  rowsum_k<<<dim3(Bn * Sn), blk, 0, stream>>>(scb, Zb);
  // out = (P' @ V) / Z via VT : grid 8 x 16 x 8 = 1024
  gemm128_k<2><<<dim3(8 * 16 * Bn), gblk, 0, stream>>>(
      scb, vtb, out, Zb, nullptr, nullptr, Dn, Sn,
      (long long)Sn * Sn, (long long)Dn * Sn, (long long)Sn * Dn, 1.f, 8, 16);
}